// Round 1
// baseline (318.258 us; speedup 1.0000x reference)
//
#include <hip/hip_runtime.h>
#include <math.h>

#define Q_SCALE (255.0f / 32.0f)
#define PHI 32
#define RHO 64
#define HH 384
#define WW 384
#define BB 8

// ---------------------------------------------------------------------------
// Kernel A: build the fused lookup table T[v][r], v in 0..7, r in 0..63.
//   h1[k] = relu(v*w1[k] + b1[k])                 (phi layer 1)
//   h2[c] = b2[c] + sum_k h1[k]*w2[k*32+c]        (phi layer 2, no relu)
//   T[v][r] = (1/9) * sum_c h2[c]*w3[c*64+r]      (rho matmul, mean folded in)
// out[b,r,h,w] = relu(b3[r] + sum_{9 neighbors} T[q_n][r])
// ---------------------------------------------------------------------------
__global__ __launch_bounds__(512) void build_table_kernel(
    const float* __restrict__ w1, const float* __restrict__ b1,
    const float* __restrict__ w2, const float* __restrict__ b2,
    const float* __restrict__ w3, float* __restrict__ T) {
    __shared__ float h2[8][PHI];
    const int t = threadIdx.x;
    if (t < 256) {
        const int v = t >> 5, c = t & 31;
        float acc = b2[c];
#pragma unroll
        for (int k = 0; k < PHI; ++k) {
            float h1 = fmaxf((float)v * w1[k] + b1[k], 0.0f);
            acc += h1 * w2[k * PHI + c];
        }
        h2[v][c] = acc;
    }
    __syncthreads();
    {
        const int v = t >> 6, r = t & 63;
        float acc = 0.0f;
#pragma unroll
        for (int c = 0; c < PHI; ++c) acc += h2[v][c] * w3[c * RHO + r];
        T[v * RHO + r] = acc * (1.0f / 9.0f);
    }
}

// ---------------------------------------------------------------------------
// Kernel B: one block per (b, h) row. 384 threads, one pixel each.
// Packed-nibble histogram of 3x3 quantized neighborhood, then 64 channels of
// 8 FMAs each against the LDS table (transposed [r][v] -> conflict-free
// wave-uniform b128 reads), coalesced dword stores.
// ---------------------------------------------------------------------------
__global__ __launch_bounds__(WW) void deepset_row_kernel(
    const float* __restrict__ x, const float* __restrict__ Tg,
    const float* __restrict__ b3, float* __restrict__ out) {
    __shared__ unsigned int qe[3][WW + 2];   // packed 1<<(4q), +2 halo cols
    __shared__ float Tl[RHO * 8];            // transposed: Tl[r*8+v]
    __shared__ float b3l[RHO];

    const int w = threadIdx.x;
    const int bh = blockIdx.x;
    const int h = bh % HH;
    const int b = bh / HH;

    // stage table (transpose v-major -> r-major) and bias into LDS
    for (int i = w; i < 8 * RHO; i += WW) {
        const int v = i >> 6, r = i & 63;
        Tl[r * 8 + v] = Tg[i];
    }
    if (w < RHO) b3l[w] = b3[w];

    // load 3 input rows, quantize, pack as 1 << (4*q); zero-padding => q=0 => 1
    const float* xb = x + (size_t)b * HH * WW;
#pragma unroll
    for (int rr = 0; rr < 3; ++rr) {
        const int hh = h - 1 + rr;
        unsigned int qv = 1u;
        if (hh >= 0 && hh < HH) {
            const float xv = xb[hh * WW + w];
            int q = (int)floorf(xv * Q_SCALE);
            q = q < 0 ? 0 : (q > 7 ? 7 : q);
            qv = 1u << (4 * q);
        }
        qe[rr][w + 1] = qv;
        if (w == 0) { qe[rr][0] = 1u; qe[rr][WW + 1] = 1u; }
    }
    __syncthreads();

    // 3x3 histogram via nibble-packed adds (max count 9 < 16: no overflow)
    unsigned int cnt = 0;
#pragma unroll
    for (int rr = 0; rr < 3; ++rr)
        cnt += qe[rr][w] + qe[rr][w + 1] + qe[rr][w + 2];

    float c[8];
#pragma unroll
    for (int v = 0; v < 8; ++v) c[v] = (float)((cnt >> (4 * v)) & 15u);

    // 64 output channels: 8 FMAs each, coalesced store
    float* ob = out + ((size_t)b * RHO * HH + h) * WW + w;
    const size_t rstride = (size_t)HH * WW;
#pragma unroll 8
    for (int r = 0; r < RHO; ++r) {
        const float4 t0 = *(const float4*)&Tl[r * 8];
        const float4 t1 = *(const float4*)&Tl[r * 8 + 4];
        float acc = b3l[r];
        acc += c[0] * t0.x + c[1] * t0.y + c[2] * t0.z + c[3] * t0.w;
        acc += c[4] * t1.x + c[5] * t1.y + c[6] * t1.z + c[7] * t1.w;
        ob[r * rstride] = fmaxf(acc, 0.0f);
    }
}

extern "C" void kernel_launch(void* const* d_in, const int* in_sizes, int n_in,
                              void* d_out, int out_size, void* d_ws, size_t ws_size,
                              hipStream_t stream) {
    const float* x  = (const float*)d_in[0];
    const float* w1 = (const float*)d_in[1];
    const float* b1 = (const float*)d_in[2];
    const float* w2 = (const float*)d_in[3];
    const float* b2 = (const float*)d_in[4];
    const float* w3 = (const float*)d_in[5];
    const float* b3 = (const float*)d_in[6];
    float* out = (float*)d_out;
    float* T   = (float*)d_ws;  // 8*64 floats = 2 KB

    build_table_kernel<<<1, 512, 0, stream>>>(w1, b1, w2, b2, w3, T);
    deepset_row_kernel<<<BB * HH, WW, 0, stream>>>(x, T, b3, out);
}